// Round 7
// baseline (23771.725 us; speedup 1.0000x reference)
//
#include <hip/hip_runtime.h>
#include <hip/hip_bf16.h>
#include <math.h>

#define SLEN 512
#define BATCH 32
#define DIM 2524
#define DK 2560      // DIM padded to 64
#define NTOK 16384   // S*B
#define LD1 2560
#define LDH 5120     // hbH row stride
#define DHALF 1280   // padded half-spectrum (1263 valid)

using f32x4 = __attribute__((ext_vector_type(4))) float;
using bfrag = __attribute__((ext_vector_type(8))) short;

__device__ __forceinline__ short f2bs(float f) {
  __hip_bfloat16 h = __float2bfloat16(f);
  return *reinterpret_cast<short*>(&h);
}
__device__ __forceinline__ float bs2f(short s) {
  __hip_bfloat16 h;
  *reinterpret_cast<short*>(&h) = s;
  return __bfloat162float(h);
}

__device__ __forceinline__ void gload16(const short* g, short* l) {
  __builtin_amdgcn_global_load_lds(
      (const __attribute__((address_space(1))) void*)g,
      (__attribute__((address_space(3))) void*)l, 16, 0, 0);
}

// ---------------- f32 -> bf16 convert with row/col offset and zero padding ----
__global__ void k_conv_pad(const float* __restrict__ in, short* __restrict__ out,
                           int Min, int Kin, int Mout, int Kout, int roff, int coff) {
  const int cpr = Kout >> 2;
  long idx = (long)blockIdx.x * 256 + threadIdx.x;
  if (idx >= (long)Mout * cpr) return;
  int r = (int)(idx / cpr);
  int c4 = (int)(idx % cpr) * 4;
  short4 o;
#pragma unroll
  for (int j = 0; j < 4; j++) {
    int c = c4 + j;
    float v = (roff + r < Min && coff + c < Kin) ? in[(long)(roff + r) * Kin + coff + c] : 0.f;
    ((short*)&o)[j] = f2bs(v);
  }
  *(short4*)(out + (long)r * Kout + c4) = o;
}

// ---- D-DFT half-spectrum table: rows [0,1280)=cos(2pi d d'/D), [1280,2560)=-sin
__global__ void k_gen_csD(short* __restrict__ out) {
  const int cpr = DK >> 2;  // 640
  long idx = (long)blockIdx.x * 256 + threadIdx.x;
  if (idx >= (long)DK * cpr) return;
  int r = (int)(idx / cpr);
  int c4 = (int)(idx % cpr) * 4;
  const int dp = (r < DHALF) ? r : r - DHALF;
  short4 o;
#pragma unroll
  for (int j = 0; j < 4; j++) {
    int c = c4 + j;
    float v = 0.f;
    if (dp <= 1262 && c < DIM) {
      int mm = (c * dp) % DIM;
      float th = (float)mm * (6.2831853071795864f / (float)DIM);
      v = (r < DHALF) ? cosf(th) : -sinf(th);
    }
    ((short*)&o)[j] = f2bs(v);
  }
  *(short4*)(out + (long)r * DK + c4) = o;
}

// ---- B-axis (size-32) DFT on half-spectrum + mirror + residual ---------------
__global__ __launch_bounds__(256) void k_bmix2(const float* __restrict__ yri,
                                               const float* __restrict__ x,
                                               float* __restrict__ t1) {
  __shared__ float yr[32][64];
  __shared__ float yi[32][64];
  __shared__ float tc[32][32];
  __shared__ float ts[32][32];
  const int s = blockIdx.x;
  const int d0 = blockIdx.y * 64;
  const int tid = threadIdx.x;
  for (int j = tid; j < 1024; j += 256) {
    int bp = j >> 5, b = j & 31;
    float th = (float)((b * bp) & 31) * (6.2831853071795864f / 32.f);
    tc[bp][b] = cosf(th);
    ts[bp][b] = sinf(th);
  }
#pragma unroll
  for (int j = 0; j < 8; j++) {
    int lin = j * 256 + tid;
    int b = lin >> 6, dd = lin & 63;
    int d = d0 + dd;
    float vr = 0.f, vi = 0.f;
    if (d < DIM) {
      const float* rowp = yri + ((long)s * 32 + b) * DK;
      if (d <= 1262) {
        vr = rowp[d];
        vi = rowp[DHALF + d];
      } else {
        int dm = DIM - d;
        vr = rowp[dm];
        vi = -rowp[DHALF + dm];
      }
    }
    yr[b][dd] = vr;
    yi[b][dd] = vi;
  }
  __syncthreads();
  const int g = tid >> 6, dd = tid & 63;
  const int d = d0 + dd;
  if (d >= DIM) return;
#pragma unroll
  for (int j = 0; j < 8; j++) {
    int bp = g * 8 + j;
    float acc = 0.f;
#pragma unroll
    for (int b = 0; b < 32; b++)
      acc += yr[b][dd] * tc[bp][b] + yi[b][dd] * ts[bp][b];
    long row = (long)s * 32 + bp;
    t1[row * DK + d] = acc + x[row * DIM + d];
  }
}

// ======= 256x256 MFMA GEMM, BK=32, 64KB LDS -> 2 blocks/CU (TLP), counted ======
// Per K-tile: ph1 {ds_read af0-3+bf0-3, stage A(t+1), lgkm, 16 MFMA}; bar;
// ph2 {ds_read af4-7, stage B(t+1), lgkm, 16 MFMA}; vmcnt(0); bar.
// The per-tile drain is covered by the co-resident second block (m114 TLP).
__global__ __launch_bounds__(512, 4) void gemm256(
    const short* __restrict__ A, long lda,
    const short* __restrict__ Bt, long ldb,
    void* __restrict__ Cout, long ldc,
    int N, int nzero, int K,
    const float* __restrict__ bias,
    const float* __restrict__ res, long ldres,
    int gn, int epi) {
  __shared__ __align__(16) short lds[32768];  // 64 KiB
  const int tid = threadIdx.x;
  const int w = tid >> 6;
  const int l = tid & 63;
  const int nwg = gridDim.x;                  // multiple of 32
  const int cpx = nwg >> 3;
  const int g = (blockIdx.x & 7) * cpx + (blockIdx.x >> 3);
  const int C = g >> 5, r32 = g & 31;
  const int nbn = gn >> 1;
  const int bm = (C / nbn) * 16 + (r32 >> 1);
  const int bn = (C % nbn) * 2 + (r32 & 1);
  const long row0 = (long)bm * 256;
  const long col0 = (long)bn * 256;
  const int wm = w >> 2, wn = w & 3;
  const short* Ab = A + row0 * lda;
  const short* Bb = Bt + col0 * ldb;
  const int rloc = l & 15;
  const int kslot = l >> 4;

  f32x4 acc[8][4] = {};
  bfrag af[4], bf[4];
  const int nt = K >> 5;

// stage half of A/B tile: L in {0,1}, K-tile kt -> buffer bufbit
#define STAGEA(bufbit, L, kt)                                                  \
  {                                                                            \
    const short* gsrc = Ab + (long)(((L) * 8 + w) * 16 + rloc) * lda +         \
                        (long)(kt) * 32 + kslot * 8;                           \
    short* ldst = &lds[(bufbit) * 16384 + ((L) * 8 + w) * 512];                \
    gload16(gsrc, ldst);                                                       \
  }
#define STAGEB(bufbit, L, kt)                                                  \
  {                                                                            \
    const short* gsrc = Bb + (long)(((L) * 8 + w) * 16 + rloc) * ldb +         \
                        (long)(kt) * 32 + kslot * 8;                           \
    short* ldst = &lds[(bufbit) * 16384 + 8192 + ((L) * 8 + w) * 512];         \
    gload16(gsrc, ldst);                                                       \
  }
#define LDAF(buf, i) \
  (*(const bfrag*)&lds[(buf) * 16384 + (wm * 8 + (i)) * 512 + kslot * 128 + rloc * 8])
#define LDBF(buf, j) \
  (*(const bfrag*)&lds[(buf) * 16384 + 8192 + (wn * 4 + (j)) * 512 + kslot * 128 + rloc * 8])

  // prologue: stage tile 0 -> buf0
  STAGEA(0, 0, 0) STAGEA(0, 1, 0)
  STAGEB(0, 0, 0) STAGEB(0, 1, 0)
  asm volatile("s_waitcnt vmcnt(0)" ::: "memory");
  __builtin_amdgcn_s_barrier();

  for (int t = 0; t < nt; ++t) {
    const int cur = t & 1, nb = cur ^ 1;
    const int ktn = (t + 1 < nt) ? t + 1 : t;  // tail: dead re-stage
    // ---- phase 1: acc[0..3][*]; stage A(t+1) ----
#pragma unroll
    for (int i = 0; i < 4; i++) af[i] = LDAF(cur, i);
#pragma unroll
    for (int j = 0; j < 4; j++) bf[j] = LDBF(cur, j);
    STAGEA(nb, 0, ktn) STAGEA(nb, 1, ktn)
    asm volatile("s_waitcnt lgkmcnt(0)" ::: "memory");
    __builtin_amdgcn_sched_barrier(0);
    __builtin_amdgcn_s_setprio(1);
#pragma unroll
    for (int i = 0; i < 4; i++)
#pragma unroll
      for (int j = 0; j < 4; j++)
        acc[i][j] = __builtin_amdgcn_mfma_f32_16x16x32_bf16(af[i], bf[j], acc[i][j], 0, 0, 0);
    __builtin_amdgcn_s_setprio(0);
    __builtin_amdgcn_s_barrier();
    // ---- phase 2: acc[4..7][*] (bf reused); stage B(t+1); vmcnt(0) ----
#pragma unroll
    for (int i = 0; i < 4; i++) af[i] = LDAF(cur, 4 + i);
    STAGEB(nb, 0, ktn) STAGEB(nb, 1, ktn)
    asm volatile("s_waitcnt lgkmcnt(0)" ::: "memory");
    __builtin_amdgcn_sched_barrier(0);
    __builtin_amdgcn_s_setprio(1);
#pragma unroll
    for (int i = 0; i < 4; i++)
#pragma unroll
      for (int j = 0; j < 4; j++)
        acc[4 + i][j] = __builtin_amdgcn_mfma_f32_16x16x32_bf16(af[i], bf[j], acc[4 + i][j], 0, 0, 0);
    __builtin_amdgcn_s_setprio(0);
    asm volatile("s_waitcnt vmcnt(0)" ::: "memory");  // t+1 landed; TLP covers stall
    __builtin_amdgcn_s_barrier();
  }

  float* outF = (float*)Cout;
  __hip_bfloat16* outB = (__hip_bfloat16*)Cout;
  const int erow = kslot * 4;
  const int ecol = rloc;
#pragma unroll
  for (int i = 0; i < 8; i++) {
#pragma unroll
    for (int e = 0; e < 4; e++) {
      long grow = row0 + wm * 128 + i * 16 + erow + e;
#pragma unroll
      for (int j = 0; j < 4; j++) {
        int gcol = (int)col0 + wn * 64 + j * 16 + ecol;
        if (gcol >= nzero) continue;
        float v = 0.f;
        if (gcol < N) {
          v = acc[i][j][e];
          if (bias) v += bias[gcol];
          if (epi == 1) v += res[grow * ldres + gcol];
          else if (epi == 2) v = 0.5f * v * (1.f + erff(v * 0.70710678118f));
          else if (epi == 4) v = fmaxf(v, 0.f);
        }
        if (epi == 6) outF[grow * ldc + gcol] += v;
        else if (epi <= 1) outF[grow * ldc + gcol] = v;
        else outB[grow * ldc + gcol] = __float2bfloat16(v);
      }
    }
  }
#undef STAGEA
#undef STAGEB
#undef LDAF
#undef LDBF
}

// ---------------- 128x128 MFMA GEMM (small batched G5/G6) ---------------------
__global__ __launch_bounds__(256) void gemm_bt(
    const short* __restrict__ A, long sA, long lda,
    const short* __restrict__ Bt, long sB, long ldb,
    void* __restrict__ Cout, long sC, long ldc,
    int N, int nzero, int K,
    const float* __restrict__ bias,
    const float* __restrict__ mask, long sMask,
    int epi) {
  __shared__ __align__(16) short As[4096];
  __shared__ __align__(16) short Bs[4096];
  const int tid = threadIdx.x;
  const int wave = tid >> 6;
  const int lane = tid & 63;
  const int z = blockIdx.z;
  const long row0 = (long)blockIdx.x * 128;
  const long col0 = (long)blockIdx.y * 128;
  const int wm = wave >> 1, wn = wave & 1;
  const short* Ab = A + z * sA + row0 * lda;
  const short* Bb = Bt + z * sB + col0 * ldb;
  const int r0 = tid >> 2, c0 = (tid & 3) * 8;
  const int r1 = r0 + 64;
  short* dA0 = As + (wave << 9);
  short* dA1 = As + 2048 + (wave << 9);
  short* dB0 = Bs + (wave << 9);
  short* dB1 = Bs + 2048 + (wave << 9);
  f32x4 acc[4][4] = {};
  for (int k0 = 0; k0 < K; k0 += 32) {
    __syncthreads();
    gload16(Ab + (long)r0 * lda + k0 + c0, dA0);
    gload16(Ab + (long)r1 * lda + k0 + c0, dA1);
    gload16(Bb + (long)r0 * ldb + k0 + c0, dB0);
    gload16(Bb + (long)r1 * ldb + k0 + c0, dB1);
    __syncthreads();
    const int kb = (lane >> 4) << 3;
    const int rr = lane & 15;
    bfrag a[4], b[4];
#pragma unroll
    for (int i = 0; i < 4; i++)
      a[i] = *(const bfrag*)&As[(wm * 64 + i * 16 + rr) * 32 + kb];
#pragma unroll
    for (int j = 0; j < 4; j++)
      b[j] = *(const bfrag*)&Bs[(wn * 64 + j * 16 + rr) * 32 + kb];
#pragma unroll
    for (int i = 0; i < 4; i++)
#pragma unroll
      for (int j = 0; j < 4; j++)
        acc[i][j] = __builtin_amdgcn_mfma_f32_16x16x32_bf16(a[i], b[j], acc[i][j], 0, 0, 0);
  }
  float* outF = (float*)Cout + z * sC;
  __hip_bfloat16* outB = (__hip_bfloat16*)Cout + z * sC;
  const float* mz = mask ? mask + z * sMask : nullptr;
  const int erow = (lane >> 4) * 4;
  const int ecol = lane & 15;
#pragma unroll
  for (int i = 0; i < 4; i++) {
#pragma unroll
    for (int e = 0; e < 4; e++) {
      long grow = row0 + wm * 64 + i * 16 + erow + e;
#pragma unroll
      for (int j = 0; j < 4; j++) {
        int gcol = (int)col0 + wn * 64 + j * 16 + ecol;
        if (gcol >= nzero) continue;
        float v = 0.f;
        if (gcol < N) {
          v = acc[i][j][e];
          if (bias) v += bias[gcol];
          if (epi == 5) v = tanhf(v * mz[gcol]);
        }
        if (epi == 5) outF[grow * ldc + gcol] = v;
        else outB[grow * ldc + gcol] = __float2bfloat16(v);
      }
    }
  }
}

// ---------------- RMSNorm over rows ----------------
__global__ __launch_bounds__(256) void k_rms(const float* __restrict__ in, long ldin,
                                             const float* __restrict__ scale,
                                             float* __restrict__ outf,
                                             short* __restrict__ outb1,
                                             short* __restrict__ outb2,
                                             const float* __restrict__ mask) {
  const long row = blockIdx.x;
  const float* rp = in + row * ldin;
  const int tid = threadIdx.x;
  float ss = 0.f;
  for (int d = tid; d < DIM; d += 256) { float v = rp[d]; ss = fmaf(v, v, ss); }
  __shared__ float red[4];
  for (int o = 32; o; o >>= 1) ss += __shfl_down(ss, o);
  if ((tid & 63) == 0) red[tid >> 6] = ss;
  __syncthreads();
  float tot = red[0] + red[1] + red[2] + red[3];
  float rms = sqrtf(tot * (1.f / (float)DIM));
  float inv = 1.f / (rms + 1e-8f);
  float mf = 1.f;
  if (mask) mf = mask[(row & 31) * SLEN + (int)(row >> 5)];
  for (int d = tid; d < DK; d += 256) {
    float v = (d < DIM) ? rp[d] * inv * scale[d] : 0.f;
    if (outf) outf[row * DK + d] = v;
    if (outb1) outb1[row * DK + d] = f2bs(v);
    if (outb2) outb2[row * DK + d] = f2bs(v * mf);
  }
}

// ---------------- emotions (s,b,d) -> emoT[b][d][s] ----------------
__global__ __launch_bounds__(256) void k_transpose(const short* __restrict__ emob,
                                                   short* __restrict__ emoT) {
  __shared__ short t[64][66];
  const int b = blockIdx.z;
  const int d0 = blockIdx.y * 64;
  const int s0 = blockIdx.x * 64;
  const int tid = threadIdx.x;
#pragma unroll
  for (int j = 0; j < 16; j++) {
    int lin = j * 256 + tid;
    int r = lin >> 6, c = lin & 63;
    int d = d0 + c;
    t[r][c] = (d < DIM) ? emob[((long)(s0 + r) * 32 + b) * DK + d] : (short)0;
  }
  __syncthreads();
#pragma unroll
  for (int j = 0; j < 16; j++) {
    int lin = j * 256 + tid;
    int r = lin >> 6, c = lin & 63;
    emoT[((long)b * 2560 + d0 + r) * SLEN + s0 + c] = t[c][r];
  }
}

// ---------------- softmax + mask renorm ----------------
__global__ __launch_bounds__(256) void k_softmax(const float* __restrict__ sc,
                                                 const float* __restrict__ mask,
                                                 float* __restrict__ alpha,
                                                 short* __restrict__ ab) {
  const int r = blockIdx.x;
  const int b = r >> 9, tq = r & 511;
  const float* row = sc + (long)r * SLEN;
  const int tid = threadIdx.x;
  const int lane = tid & 63, wv = tid >> 6;
  __shared__ float red[4];
  float v0 = row[tid], v1 = row[tid + 256];
  float m = fmaxf(v0, v1);
  for (int o = 32; o; o >>= 1) m = fmaxf(m, __shfl_down(m, o));
  if (lane == 0) red[wv] = m;
  __syncthreads();
  m = fmaxf(fmaxf(red[0], red[1]), fmaxf(red[2], red[3]));
  __syncthreads();
  float e0 = expf(v0 - m), e1 = expf(v1 - m);
  float s = e0 + e1;
  for (int o = 32; o; o >>= 1) s += __shfl_down(s, o);
  if (lane == 0) red[wv] = s;
  __syncthreads();
  s = red[0] + red[1] + red[2] + red[3];
  __syncthreads();
  float m0 = mask[b * SLEN + tid], m1 = mask[b * SLEN + tid + 256];
  float a0 = e0 / s * m0, a1 = e1 / s * m1;
  float s2 = a0 + a1;
  for (int o = 32; o; o >>= 1) s2 += __shfl_down(s2, o);
  if (lane == 0) red[wv] = s2;
  __syncthreads();
  s2 = red[0] + red[1] + red[2] + red[3];
  float f0 = a0 / s2, f1 = a1 / s2;
  long ob = ((long)tq * BATCH + b) * SLEN;
  alpha[ob + tid] = f0;
  alpha[ob + tid + 256] = f1;
  ab[(long)r * SLEN + tid] = f2bs(f0);
  ab[(long)r * SLEN + tid + 256] = f2bs(f1);
}

// ---------------- fc head ----------------
__global__ __launch_bounds__(256) void k_logprob(const short* __restrict__ hid,
                                                 const float* __restrict__ fcw,
                                                 const float* __restrict__ fcb,
                                                 float* __restrict__ out) {
  const int tok = blockIdx.x * 4 + (threadIdx.x >> 6);
  const int lane = threadIdx.x & 63;
  const short* hr = hid + (long)tok * DK;
  float p0 = 0, p1 = 0, p2 = 0, p3 = 0, p4 = 0, p5 = 0;
  for (int d = lane; d < DIM; d += 64) {
    float h = bs2f(hr[d]);
    p0 += h * fcw[d];
    p1 += h * fcw[DIM + d];
    p2 += h * fcw[2 * DIM + d];
    p3 += h * fcw[3 * DIM + d];
    p4 += h * fcw[4 * DIM + d];
    p5 += h * fcw[5 * DIM + d];
  }
  for (int o = 32; o; o >>= 1) {
    p0 += __shfl_down(p0, o); p1 += __shfl_down(p1, o); p2 += __shfl_down(p2, o);
    p3 += __shfl_down(p3, o); p4 += __shfl_down(p4, o); p5 += __shfl_down(p5, o);
  }
  if (lane == 0) {
    float* o6 = out + (long)tok * 6;
    o6[0] = p0 + fcb[0]; o6[1] = p1 + fcb[1]; o6[2] = p2 + fcb[2];
    o6[3] = p3 + fcb[3]; o6[4] = p4 + fcb[4]; o6[5] = p5 + fcb[5];
  }
}

extern "C" void kernel_launch(void* const* d_in, const int* in_sizes, int n_in,
                              void* d_out, int out_size, void* d_ws, size_t ws_size,
                              hipStream_t stream) {
  const float* x    = (const float*)d_in[0];
  const float* mask = (const float*)d_in[2];
  const float* n1s  = (const float*)d_in[3];
  const float* n2s  = (const float*)d_in[4];
  const float* w1   = (const float*)d_in[5];
  const float* b1   = (const float*)d_in[6];
  const float* w2   = (const float*)d_in[7];
  const float* b2   = (const float*)d_in[8];
  const float* attw = (const float*)d_in[9];
  const float* att_bias = (const float*)d_in[10];
  const float* linw = (const float*)d_in[11];
  const float* lin_bias = (const float*)d_in[12];
  const float* fcw  = (const float*)d_in[13];
  const float* fcb  = (const float*)d_in[14];
  float* out = (float*)d_out;

  const size_t R2 = 0;            // yri -> hbH -> emob+mmb -> scr+ab
  const size_t R3 = 167772160;    // t1/x1f/t2 -> atb(lo)+emoT(hi)
  const size_t R4 = 335544320;    // xb -> x1b -> qb -> hidb
  const size_t RF = 419430400;    // staged weight half / DFT table
  const size_t TOTAL = 445644800;
  if (ws_size < TOTAL) return;

  char* ws = (char*)d_ws;
  float* yri  = (float*)(ws + R2);
  short* hbH  = (short*)(ws + R2);
  short* emob = (short*)(ws + R2);
  short* mmb  = (short*)(ws + R2 + 83886080);
  float* scr  = (float*)(ws + R2);
  short* ab   = (short*)(ws + R2 + 33554432);
  float* t1   = (float*)(ws + R3);
  float* x1f  = t1;
  float* t2   = t1;
  short* atb  = (short*)(ws + R3);
  short* emoT = (short*)(ws + R3 + 83886080);
  short* xb   = (short*)(ws + R4);
  short* x1b  = (short*)(ws + R4);
  short* qb   = (short*)(ws + R4);
  short* hidb = (short*)(ws + R4);
  short* wtb  = (short*)(ws + RF);

  dim3 blk(256), blk5(512);
  k_conv_pad<<<dim3((16384 * 640 + 255) / 256), blk, 0, stream>>>(x, xb, 16384, 2524, 16384, 2560, 0, 0);
  k_gen_csD<<<dim3((2560 * 640 + 255) / 256), blk, 0, stream>>>(wtb);
  gemm256<<<dim3(640), blk5, 0, stream>>>(xb, 2560, wtb, 2560, yri, 2560,
                                          2560, 2560, 2560, nullptr, nullptr, 0, 10, 0);
  k_bmix2<<<dim3(512, 40), blk, 0, stream>>>(yri, x, t1);
  k_rms<<<dim3(NTOK), blk, 0, stream>>>(t1, LD1, n1s, x1f, x1b, nullptr, nullptr);
  k_conv_pad<<<dim3((5120 * 640 + 255) / 256), blk, 0, stream>>>(w1, wtb, 10096, 2524, 5120, 2560, 0, 0);
  gemm256<<<dim3(1280), blk5, 0, stream>>>(x1b, DK, wtb, DK, hbH, LDH,
                                           5120, 5120, DK, b1, nullptr, 0, 20, 2);
  k_conv_pad<<<dim3((2560 * 1280 + 255) / 256), blk, 0, stream>>>(w2, wtb, 2524, 10096, 2560, 5120, 0, 0);
  gemm256<<<dim3(640), blk5, 0, stream>>>(hbH, LDH, wtb, LDH, t2, DK,
                                          DIM, 2560, LDH, b2, x1f, DK, 10, 1);
  k_conv_pad<<<dim3((5120 * 640 + 255) / 256), blk, 0, stream>>>(w1, wtb, 10096, 2524, 5120, 2560, 5120, 0);
  gemm256<<<dim3(1280), blk5, 0, stream>>>(x1b, DK, wtb, DK, hbH, LDH,
                                           4976, 5120, DK, b1 + 5120, nullptr, 0, 20, 2);
  k_conv_pad<<<dim3((2560 * 1280 + 255) / 256), blk, 0, stream>>>(w2, wtb, 2524, 10096, 2560, 5120, 0, 5120);
  gemm256<<<dim3(640), blk5, 0, stream>>>(hbH, LDH, wtb, LDH, t2, DK,
                                          2560, 2560, LDH, nullptr, nullptr, 0, 10, 6);
  k_rms<<<dim3(NTOK), blk, 0, stream>>>(t2, DK, n2s, nullptr, emob, mmb, mask);
  k_transpose<<<dim3(8, 40, 32), blk, 0, stream>>>(emob, emoT);
  k_conv_pad<<<dim3((2560 * 640 + 255) / 256), blk, 0, stream>>>(attw, wtb, 2524, 2524, 2560, 2560, 0, 0);
  gemm256<<<dim3(640), blk5, 0, stream>>>(emob, DK, wtb, DK, qb, DK,
                                          DIM, 2560, DK, att_bias, nullptr, 0, 10, 3);
  gemm_bt<<<dim3(4, 4, 32), blk, 0, stream>>>(qb, DK, (long)BATCH * DK, mmb, DK, (long)BATCH * DK,
                                              scr, (long)SLEN * SLEN, SLEN,
                                              SLEN, SLEN, DK, nullptr, mask, SLEN, 5);
  k_softmax<<<dim3(NTOK), blk, 0, stream>>>(scr, mask, out + 98304, ab);
  gemm_bt<<<dim3(4, 20, 32), blk, 0, stream>>>(ab, (long)SLEN * SLEN, SLEN, emoT, (long)2560 * SLEN, SLEN,
                                               atb, DK, (long)BATCH * DK,
                                               2560, 2560, SLEN, nullptr, nullptr, 0, 3);
  k_conv_pad<<<dim3((2560 * 640 + 255) / 256), blk, 0, stream>>>(linw, wtb, 2524, 2524, 2560, 2560, 0, 0);
  gemm256<<<dim3(640), blk5, 0, stream>>>(atb, DK, wtb, DK, hidb, DK,
                                          DIM, 2560, DK, lin_bias, nullptr, 0, 10, 4);
  k_logprob<<<dim3(NTOK / 4), blk, 0, stream>>>(hidb, fcw, fcb, out);
}

// Round 8
// 5023.452 us; speedup vs baseline: 4.7321x; 4.7321x over previous
//
#include <hip/hip_runtime.h>
#include <hip/hip_bf16.h>
#include <math.h>

#define SLEN 512
#define BATCH 32
#define DIM 2524
#define DK 2560      // DIM padded to 64
#define NTOK 16384   // S*B
#define LD1 2560
#define LDH 5120     // hbH row stride
#define DHALF 1280   // padded half-spectrum (1263 valid)

using f32x4 = __attribute__((ext_vector_type(4))) float;
using bfrag = __attribute__((ext_vector_type(8))) short;

__device__ __forceinline__ short f2bs(float f) {
  __hip_bfloat16 h = __float2bfloat16(f);
  return *reinterpret_cast<short*>(&h);
}
__device__ __forceinline__ float bs2f(short s) {
  __hip_bfloat16 h;
  *reinterpret_cast<short*>(&h) = s;
  return __bfloat162float(h);
}

__device__ __forceinline__ void gload16(const short* g, short* l) {
  __builtin_amdgcn_global_load_lds(
      (const __attribute__((address_space(1))) void*)g,
      (__attribute__((address_space(3))) void*)l, 16, 0, 0);
}

// ---------------- f32 -> bf16 convert with row/col offset and zero padding ----
__global__ void k_conv_pad(const float* __restrict__ in, short* __restrict__ out,
                           int Min, int Kin, int Mout, int Kout, int roff, int coff) {
  const int cpr = Kout >> 2;
  long idx = (long)blockIdx.x * 256 + threadIdx.x;
  if (idx >= (long)Mout * cpr) return;
  int r = (int)(idx / cpr);
  int c4 = (int)(idx % cpr) * 4;
  short4 o;
#pragma unroll
  for (int j = 0; j < 4; j++) {
    int c = c4 + j;
    float v = (roff + r < Min && coff + c < Kin) ? in[(long)(roff + r) * Kin + coff + c] : 0.f;
    ((short*)&o)[j] = f2bs(v);
  }
  *(short4*)(out + (long)r * Kout + c4) = o;
}

// ---- D-DFT half-spectrum table: rows [0,1280)=cos(2pi d d'/D), [1280,2560)=-sin
__global__ void k_gen_csD(short* __restrict__ out) {
  const int cpr = DK >> 2;  // 640
  long idx = (long)blockIdx.x * 256 + threadIdx.x;
  if (idx >= (long)DK * cpr) return;
  int r = (int)(idx / cpr);
  int c4 = (int)(idx % cpr) * 4;
  const int dp = (r < DHALF) ? r : r - DHALF;
  short4 o;
#pragma unroll
  for (int j = 0; j < 4; j++) {
    int c = c4 + j;
    float v = 0.f;
    if (dp <= 1262 && c < DIM) {
      int mm = (c * dp) % DIM;
      float th = (float)mm * (6.2831853071795864f / (float)DIM);
      v = (r < DHALF) ? cosf(th) : -sinf(th);
    }
    ((short*)&o)[j] = f2bs(v);
  }
  *(short4*)(out + (long)r * DK + c4) = o;
}

// ---- B-axis (size-32) DFT on half-spectrum + mirror + residual ---------------
__global__ __launch_bounds__(256) void k_bmix2(const float* __restrict__ yri,
                                               const float* __restrict__ x,
                                               float* __restrict__ t1) {
  __shared__ float yr[32][64];
  __shared__ float yi[32][64];
  __shared__ float tc[32][32];
  __shared__ float ts[32][32];
  const int s = blockIdx.x;
  const int d0 = blockIdx.y * 64;
  const int tid = threadIdx.x;
  for (int j = tid; j < 1024; j += 256) {
    int bp = j >> 5, b = j & 31;
    float th = (float)((b * bp) & 31) * (6.2831853071795864f / 32.f);
    tc[bp][b] = cosf(th);
    ts[bp][b] = sinf(th);
  }
#pragma unroll
  for (int j = 0; j < 8; j++) {
    int lin = j * 256 + tid;
    int b = lin >> 6, dd = lin & 63;
    int d = d0 + dd;
    float vr = 0.f, vi = 0.f;
    if (d < DIM) {
      const float* rowp = yri + ((long)s * 32 + b) * DK;
      if (d <= 1262) {
        vr = rowp[d];
        vi = rowp[DHALF + d];
      } else {
        int dm = DIM - d;
        vr = rowp[dm];
        vi = -rowp[DHALF + dm];
      }
    }
    yr[b][dd] = vr;
    yi[b][dd] = vi;
  }
  __syncthreads();
  const int g = tid >> 6, dd = tid & 63;
  const int d = d0 + dd;
  if (d >= DIM) return;
#pragma unroll
  for (int j = 0; j < 8; j++) {
    int bp = g * 8 + j;
    float acc = 0.f;
#pragma unroll
    for (int b = 0; b < 32; b++)
      acc += yr[b][dd] * tc[bp][b] + yi[b][dd] * ts[bp][b];
    long row = (long)s * 32 + bp;
    t1[row * DK + d] = acc + x[row * DIM + d];
  }
}

// ===== 256x256 MFMA GEMM, BK=32, 4-deep LDS ring, 3-tile prefetch, counted =====
// Per tile t (2 phases): ph1 {ds_read af0-3+bf0-3, stage A(t+3), lgkm, 16 MFMA};
// ph2 {ds_read af4-7, stage B(t+3), lgkm, 16 MFMA}; vmcnt(8); barrier.
// vmcnt(8) retires exactly {A,B}(t+1) (issued 2 tiles earlier -> ~2000cy cover);
// outstanding stays at 8 ({A,B}(t+2),(t+3)) -- never drained in the loop.
// Ring buf (t&3): stage of t+3 hits buf (t-1)&3, drained before end-of-(t-1) bar.
__global__ __launch_bounds__(512, 2) void gemm256(
    const short* __restrict__ A, long lda,
    const short* __restrict__ Bt, long ldb,
    void* __restrict__ Cout, long ldc,
    int N, int nzero, int K,
    const float* __restrict__ bias,
    const float* __restrict__ res, long ldres,
    int gn, int epi) {
  __shared__ __align__(16) short lds[65536];  // 128 KiB = 4 ring slots x 32 KB
  const int tid = threadIdx.x;
  const int w = tid >> 6;
  const int l = tid & 63;
  const int nwg = gridDim.x;                  // multiple of 32
  const int cpx = nwg >> 3;
  const int g = (blockIdx.x & 7) * cpx + (blockIdx.x >> 3);
  const int C = g >> 5, r32 = g & 31;
  const int nbn = gn >> 1;
  const int bm = (C / nbn) * 16 + (r32 >> 1);
  const int bn = (C % nbn) * 2 + (r32 & 1);
  const long row0 = (long)bm * 256;
  const long col0 = (long)bn * 256;
  const int wm = w >> 2, wn = w & 3;
  const short* Ab = A + row0 * lda;
  const short* Bb = Bt + col0 * ldb;
  const int rloc = l & 15;
  const int kslot = l >> 4;

  f32x4 acc[8][4] = {};
  bfrag af[4], bf[4];
  const int nt = K >> 5;

// stage half of A/B K32-tile: L in {0,1}, K-tile kt -> ring slot bufidx
#define STAGEA(bufidx, L, kt)                                                  \
  {                                                                            \
    const short* gsrc = Ab + (long)(((L) * 8 + w) * 16 + rloc) * lda +         \
                        (long)(kt) * 32 + kslot * 8;                           \
    short* ldst = &lds[(bufidx) * 16384 + ((L) * 8 + w) * 512];                \
    gload16(gsrc, ldst);                                                       \
  }
#define STAGEB(bufidx, L, kt)                                                  \
  {                                                                            \
    const short* gsrc = Bb + (long)(((L) * 8 + w) * 16 + rloc) * ldb +         \
                        (long)(kt) * 32 + kslot * 8;                           \
    short* ldst = &lds[(bufidx) * 16384 + 8192 + ((L) * 8 + w) * 512];         \
    gload16(gsrc, ldst);                                                       \
  }
#define LDAF(buf, i) \
  (*(const bfrag*)&lds[(buf) * 16384 + (wm * 8 + (i)) * 512 + kslot * 128 + rloc * 8])
#define LDBF(buf, j) \
  (*(const bfrag*)&lds[(buf) * 16384 + 8192 + (wn * 4 + (j)) * 512 + kslot * 128 + rloc * 8])

  // prologue: stage tiles 0,1,2 into slots 0,1,2 (12 loads)
  STAGEA(0, 0, 0) STAGEA(0, 1, 0) STAGEB(0, 0, 0) STAGEB(0, 1, 0)
  STAGEA(1, 0, 1) STAGEA(1, 1, 1) STAGEB(1, 0, 1) STAGEB(1, 1, 1)
  STAGEA(2, 0, 2) STAGEA(2, 1, 2) STAGEB(2, 0, 2) STAGEB(2, 1, 2)
  asm volatile("s_waitcnt vmcnt(8)" ::: "memory");  // tile 0 landed
  __builtin_amdgcn_s_barrier();

  for (int t = 0; t < nt; ++t) {
    const int bc = t & 3;
    const int bs = (t + 3) & 3;
    const int kt3 = (t + 3 < nt) ? t + 3 : nt - 1;  // tail: dead re-stage
    // ---- phase 1: acc[0..3][*]; stage A(t+3) ----
#pragma unroll
    for (int i = 0; i < 4; i++) af[i] = LDAF(bc, i);
#pragma unroll
    for (int j = 0; j < 4; j++) bf[j] = LDBF(bc, j);
    STAGEA(bs, 0, kt3) STAGEA(bs, 1, kt3)
    asm volatile("s_waitcnt lgkmcnt(0)" ::: "memory");
    __builtin_amdgcn_sched_barrier(0);
    __builtin_amdgcn_s_setprio(1);
#pragma unroll
    for (int i = 0; i < 4; i++)
#pragma unroll
      for (int j = 0; j < 4; j++)
        acc[i][j] = __builtin_amdgcn_mfma_f32_16x16x32_bf16(af[i], bf[j], acc[i][j], 0, 0, 0);
    __builtin_amdgcn_s_setprio(0);
    // ---- phase 2: acc[4..7][*] (bf reused); stage B(t+3) ----
#pragma unroll
    for (int i = 0; i < 4; i++) af[i] = LDAF(bc, 4 + i);
    STAGEB(bs, 0, kt3) STAGEB(bs, 1, kt3)
    asm volatile("s_waitcnt lgkmcnt(0)" ::: "memory");
    __builtin_amdgcn_sched_barrier(0);
    __builtin_amdgcn_s_setprio(1);
#pragma unroll
    for (int i = 0; i < 4; i++)
#pragma unroll
      for (int j = 0; j < 4; j++)
        acc[4 + i][j] = __builtin_amdgcn_mfma_f32_16x16x32_bf16(af[i], bf[j], acc[4 + i][j], 0, 0, 0);
    __builtin_amdgcn_s_setprio(0);
    asm volatile("s_waitcnt vmcnt(8)" ::: "memory");  // (t+1) landed; 8 stay in flight
    __builtin_amdgcn_s_barrier();
  }

  float* outF = (float*)Cout;
  __hip_bfloat16* outB = (__hip_bfloat16*)Cout;
  const int erow = kslot * 4;
  const int ecol = rloc;
#pragma unroll
  for (int i = 0; i < 8; i++) {
#pragma unroll
    for (int e = 0; e < 4; e++) {
      long grow = row0 + wm * 128 + i * 16 + erow + e;
#pragma unroll
      for (int j = 0; j < 4; j++) {
        int gcol = (int)col0 + wn * 64 + j * 16 + ecol;
        if (gcol >= nzero) continue;
        float v = 0.f;
        if (gcol < N) {
          v = acc[i][j][e];
          if (bias) v += bias[gcol];
          if (epi == 1) v += res[grow * ldres + gcol];
          else if (epi == 2) v = 0.5f * v * (1.f + erff(v * 0.70710678118f));
          else if (epi == 4) v = fmaxf(v, 0.f);
        }
        if (epi == 6) outF[grow * ldc + gcol] += v;
        else if (epi <= 1) outF[grow * ldc + gcol] = v;
        else outB[grow * ldc + gcol] = __float2bfloat16(v);
      }
    }
  }
#undef STAGEA
#undef STAGEB
#undef LDAF
#undef LDBF
}

// ---------------- 128x128 MFMA GEMM (small batched G5/G6) ---------------------
__global__ __launch_bounds__(256) void gemm_bt(
    const short* __restrict__ A, long sA, long lda,
    const short* __restrict__ Bt, long sB, long ldb,
    void* __restrict__ Cout, long sC, long ldc,
    int N, int nzero, int K,
    const float* __restrict__ bias,
    const float* __restrict__ mask, long sMask,
    int epi) {
  __shared__ __align__(16) short As[4096];
  __shared__ __align__(16) short Bs[4096];
  const int tid = threadIdx.x;
  const int wave = tid >> 6;
  const int lane = tid & 63;
  const int z = blockIdx.z;
  const long row0 = (long)blockIdx.x * 128;
  const long col0 = (long)blockIdx.y * 128;
  const int wm = wave >> 1, wn = wave & 1;
  const short* Ab = A + z * sA + row0 * lda;
  const short* Bb = Bt + z * sB + col0 * ldb;
  const int r0 = tid >> 2, c0 = (tid & 3) * 8;
  const int r1 = r0 + 64;
  short* dA0 = As + (wave << 9);
  short* dA1 = As + 2048 + (wave << 9);
  short* dB0 = Bs + (wave << 9);
  short* dB1 = Bs + 2048 + (wave << 9);
  f32x4 acc[4][4] = {};
  for (int k0 = 0; k0 < K; k0 += 32) {
    __syncthreads();
    gload16(Ab + (long)r0 * lda + k0 + c0, dA0);
    gload16(Ab + (long)r1 * lda + k0 + c0, dA1);
    gload16(Bb + (long)r0 * ldb + k0 + c0, dB0);
    gload16(Bb + (long)r1 * ldb + k0 + c0, dB1);
    __syncthreads();
    const int kb = (lane >> 4) << 3;
    const int rr = lane & 15;
    bfrag a[4], b[4];
#pragma unroll
    for (int i = 0; i < 4; i++)
      a[i] = *(const bfrag*)&As[(wm * 64 + i * 16 + rr) * 32 + kb];
#pragma unroll
    for (int j = 0; j < 4; j++)
      b[j] = *(const bfrag*)&Bs[(wn * 64 + j * 16 + rr) * 32 + kb];
#pragma unroll
    for (int i = 0; i < 4; i++)
#pragma unroll
      for (int j = 0; j < 4; j++)
        acc[i][j] = __builtin_amdgcn_mfma_f32_16x16x32_bf16(a[i], b[j], acc[i][j], 0, 0, 0);
  }
  float* outF = (float*)Cout + z * sC;
  __hip_bfloat16* outB = (__hip_bfloat16*)Cout + z * sC;
  const float* mz = mask ? mask + z * sMask : nullptr;
  const int erow = (lane >> 4) * 4;
  const int ecol = lane & 15;
#pragma unroll
  for (int i = 0; i < 4; i++) {
#pragma unroll
    for (int e = 0; e < 4; e++) {
      long grow = row0 + wm * 64 + i * 16 + erow + e;
#pragma unroll
      for (int j = 0; j < 4; j++) {
        int gcol = (int)col0 + wn * 64 + j * 16 + ecol;
        if (gcol >= nzero) continue;
        float v = 0.f;
        if (gcol < N) {
          v = acc[i][j][e];
          if (bias) v += bias[gcol];
          if (epi == 5) v = tanhf(v * mz[gcol]);
        }
        if (epi == 5) outF[grow * ldc + gcol] = v;
        else outB[grow * ldc + gcol] = __float2bfloat16(v);
      }
    }
  }
}

// ---------------- RMSNorm over rows ----------------
__global__ __launch_bounds__(256) void k_rms(const float* __restrict__ in, long ldin,
                                             const float* __restrict__ scale,
                                             float* __restrict__ outf,
                                             short* __restrict__ outb1,
                                             short* __restrict__ outb2,
                                             const float* __restrict__ mask) {
  const long row = blockIdx.x;
  const float* rp = in + row * ldin;
  const int tid = threadIdx.x;
  float ss = 0.f;
  for (int d = tid; d < DIM; d += 256) { float v = rp[d]; ss = fmaf(v, v, ss); }
  __shared__ float red[4];
  for (int o = 32; o; o >>= 1) ss += __shfl_down(ss, o);
  if ((tid & 63) == 0) red[tid >> 6] = ss;
  __syncthreads();
  float tot = red[0] + red[1] + red[2] + red[3];
  float rms = sqrtf(tot * (1.f / (float)DIM));
  float inv = 1.f / (rms + 1e-8f);
  float mf = 1.f;
  if (mask) mf = mask[(row & 31) * SLEN + (int)(row >> 5)];
  for (int d = tid; d < DK; d += 256) {
    float v = (d < DIM) ? rp[d] * inv * scale[d] : 0.f;
    if (outf) outf[row * DK + d] = v;
    if (outb1) outb1[row * DK + d] = f2bs(v);
    if (outb2) outb2[row * DK + d] = f2bs(v * mf);
  }
}

// ---------------- emotions (s,b,d) -> emoT[b][d][s] ----------------
__global__ __launch_bounds__(256) void k_transpose(const short* __restrict__ emob,
                                                   short* __restrict__ emoT) {
  __shared__ short t[64][66];
  const int b = blockIdx.z;
  const int d0 = blockIdx.y * 64;
  const int s0 = blockIdx.x * 64;
  const int tid = threadIdx.x;
#pragma unroll
  for (int j = 0; j < 16; j++) {
    int lin = j * 256 + tid;
    int r = lin >> 6, c = lin & 63;
    int d = d0 + c;
    t[r][c] = (d < DIM) ? emob[((long)(s0 + r) * 32 + b) * DK + d] : (short)0;
  }
  __syncthreads();
#pragma unroll
  for (int j = 0; j < 16; j++) {
    int lin = j * 256 + tid;
    int r = lin >> 6, c = lin & 63;
    emoT[((long)b * 2560 + d0 + r) * SLEN + s0 + c] = t[c][r];
  }
}

// ---------------- softmax + mask renorm ----------------
__global__ __launch_bounds__(256) void k_softmax(const float* __restrict__ sc,
                                                 const float* __restrict__ mask,
                                                 float* __restrict__ alpha,
                                                 short* __restrict__ ab) {
  const int r = blockIdx.x;
  const int b = r >> 9, tq = r & 511;
  const float* row = sc + (long)r * SLEN;
  const int tid = threadIdx.x;
  const int lane = tid & 63, wv = tid >> 6;
  __shared__ float red[4];
  float v0 = row[tid], v1 = row[tid + 256];
  float m = fmaxf(v0, v1);
  for (int o = 32; o; o >>= 1) m = fmaxf(m, __shfl_down(m, o));
  if (lane == 0) red[wv] = m;
  __syncthreads();
  m = fmaxf(fmaxf(red[0], red[1]), fmaxf(red[2], red[3]));
  __syncthreads();
  float e0 = expf(v0 - m), e1 = expf(v1 - m);
  float s = e0 + e1;
  for (int o = 32; o; o >>= 1) s += __shfl_down(s, o);
  if (lane == 0) red[wv] = s;
  __syncthreads();
  s = red[0] + red[1] + red[2] + red[3];
  __syncthreads();
  float m0 = mask[b * SLEN + tid], m1 = mask[b * SLEN + tid + 256];
  float a0 = e0 / s * m0, a1 = e1 / s * m1;
  float s2 = a0 + a1;
  for (int o = 32; o; o >>= 1) s2 += __shfl_down(s2, o);
  if (lane == 0) red[wv] = s2;
  __syncthreads();
  s2 = red[0] + red[1] + red[2] + red[3];
  float f0 = a0 / s2, f1 = a1 / s2;
  long ob = ((long)tq * BATCH + b) * SLEN;
  alpha[ob + tid] = f0;
  alpha[ob + tid + 256] = f1;
  ab[(long)r * SLEN + tid] = f2bs(f0);
  ab[(long)r * SLEN + tid + 256] = f2bs(f1);
}

// ---------------- fc head ----------------
__global__ __launch_bounds__(256) void k_logprob(const short* __restrict__ hid,
                                                 const float* __restrict__ fcw,
                                                 const float* __restrict__ fcb,
                                                 float* __restrict__ out) {
  const int tok = blockIdx.x * 4 + (threadIdx.x >> 6);
  const int lane = threadIdx.x & 63;
  const short* hr = hid + (long)tok * DK;
  float p0 = 0, p1 = 0, p2 = 0, p3 = 0, p4 = 0, p5 = 0;
  for (int d = lane; d < DIM; d += 64) {
    float h = bs2f(hr[d]);
    p0 += h * fcw[d];
    p1 += h * fcw[DIM + d];
    p2 += h * fcw[2 * DIM + d];
    p3 += h * fcw[3 * DIM + d];
    p4 += h * fcw[4 * DIM + d];
    p5 += h * fcw[5 * DIM + d];
  }
  for (int o = 32; o; o >>= 1) {
    p0 += __shfl_down(p0, o); p1 += __shfl_down(p1, o); p2 += __shfl_down(p2, o);
    p3 += __shfl_down(p3, o); p4 += __shfl_down(p4, o); p5 += __shfl_down(p5, o);
  }
  if (lane == 0) {
    float* o6 = out + (long)tok * 6;
    o6[0] = p0 + fcb[0]; o6[1] = p1 + fcb[1]; o6[2] = p2 + fcb[2];
    o6[3] = p3 + fcb[3]; o6[4] = p4 + fcb[4]; o6[5] = p5 + fcb[5];
  }
}

extern "C" void kernel_launch(void* const* d_in, const int* in_sizes, int n_in,
                              void* d_out, int out_size, void* d_ws, size_t ws_size,
                              hipStream_t stream) {
  const float* x    = (const float*)d_in[0];
  const float* mask = (const float*)d_in[2];
  const float* n1s  = (const float*)d_in[3];
  const float* n2s  = (const float*)d_in[4];
  const float* w1   = (const float*)d_in[5];
  const float* b1   = (const float*)d_in[6];
  const float* w2   = (const float*)d_in[7];
  const float* b2   = (const float*)d_in[8];
  const float* attw = (const float*)d_in[9];
  const float* att_bias = (const float*)d_in[10];
  const float* linw = (const float*)d_in[11];
  const float* lin_bias = (const float*)d_in[12];
  const float* fcw  = (const float*)d_in[13];
  const float* fcb  = (const float*)d_in[14];
  float* out = (float*)d_out;

  const size_t R2 = 0;            // yri -> hbH -> emob+mmb -> scr+ab
  const size_t R3 = 167772160;    // t1/x1f/t2 -> atb(lo)+emoT(hi)
  const size_t R4 = 335544320;    // xb -> x1b -> qb -> hidb
  const size_t RF = 419430400;    // staged weight half / DFT table
  const size_t TOTAL = 445644800;
  if (ws_size < TOTAL) return;

  char* ws = (char*)d_ws;
  float* yri  = (float*)(ws + R2);
  short* hbH  = (short*)(ws + R2);
  short* emob = (short*)(ws + R2);
  short* mmb  = (short*)(ws + R2 + 83886080);
  float* scr  = (float*)(ws + R2);
  short* ab   = (short*)(ws + R2 + 33554432);
  float* t1   = (float*)(ws + R3);
  float* x1f  = t1;
  float* t2   = t1;
  short* atb  = (short*)(ws + R3);
  short* emoT = (short*)(ws + R3 + 83886080);
  short* xb   = (short*)(ws + R4);
  short* x1b  = (short*)(ws + R4);
  short* qb   = (short*)(ws + R4);
  short* hidb = (short*)(ws + R4);
  short* wtb  = (short*)(ws + RF);

  dim3 blk(256), blk5(512);
  k_conv_pad<<<dim3((16384 * 640 + 255) / 256), blk, 0, stream>>>(x, xb, 16384, 2524, 16384, 2560, 0, 0);
  k_gen_csD<<<dim3((2560 * 640 + 255) / 256), blk, 0, stream>>>(wtb);
  gemm256<<<dim3(640), blk5, 0, stream>>>(xb, 2560, wtb, 2560, yri, 2560,
                                          2560, 2560, 2560, nullptr, nullptr, 0, 10, 0);
  k_bmix2<<<dim3(512, 40), blk, 0, stream>>>(yri, x, t1);
  k_rms<<<dim3(NTOK), blk, 0, stream>>>(t1, LD1, n1s, x1f, x1b, nullptr, nullptr);
  k_conv_pad<<<dim3((5120 * 640 + 255) / 256), blk, 0, stream>>>(w1, wtb, 10096, 2524, 5120, 2560, 0, 0);
  gemm256<<<dim3(1280), blk5, 0, stream>>>(x1b, DK, wtb, DK, hbH, LDH,
                                           5120, 5120, DK, b1, nullptr, 0, 20, 2);
  k_conv_pad<<<dim3((2560 * 1280 + 255) / 256), blk, 0, stream>>>(w2, wtb, 2524, 10096, 2560, 5120, 0, 0);
  gemm256<<<dim3(640), blk5, 0, stream>>>(hbH, LDH, wtb, LDH, t2, DK,
                                          DIM, 2560, LDH, b2, x1f, DK, 10, 1);
  k_conv_pad<<<dim3((5120 * 640 + 255) / 256), blk, 0, stream>>>(w1, wtb, 10096, 2524, 5120, 2560, 5120, 0);
  gemm256<<<dim3(1280), blk5, 0, stream>>>(x1b, DK, wtb, DK, hbH, LDH,
                                           4976, 5120, DK, b1 + 5120, nullptr, 0, 20, 2);
  k_conv_pad<<<dim3((2560 * 1280 + 255) / 256), blk, 0, stream>>>(w2, wtb, 2524, 10096, 2560, 5120, 0, 5120);
  gemm256<<<dim3(640), blk5, 0, stream>>>(hbH, LDH, wtb, LDH, t2, DK,
                                          2560, 2560, LDH, nullptr, nullptr, 0, 10, 6);
  k_rms<<<dim3(NTOK), blk, 0, stream>>>(t2, DK, n2s, nullptr, emob, mmb, mask);
  k_transpose<<<dim3(8, 40, 32), blk, 0, stream>>>(emob, emoT);
  k_conv_pad<<<dim3((2560 * 640 + 255) / 256), blk, 0, stream>>>(attw, wtb, 2524, 2524, 2560, 2560, 0, 0);
  gemm256<<<dim3(640), blk5, 0, stream>>>(emob, DK, wtb, DK, qb, DK,
                                          DIM, 2560, DK, att_bias, nullptr, 0, 10, 3);
  gemm_bt<<<dim3(4, 4, 32), blk, 0, stream>>>(qb, DK, (long)BATCH * DK, mmb, DK, (long)BATCH * DK,
                                              scr, (long)SLEN * SLEN, SLEN,
                                              SLEN, SLEN, DK, nullptr, mask, SLEN, 5);
  k_softmax<<<dim3(NTOK), blk, 0, stream>>>(scr, mask, out + 98304, ab);
  gemm_bt<<<dim3(4, 20, 32), blk, 0, stream>>>(ab, (long)SLEN * SLEN, SLEN, emoT, (long)2560 * SLEN, SLEN,
                                               atb, DK, (long)BATCH * DK,
                                               2560, 2560, SLEN, nullptr, nullptr, 0, 3);
  k_conv_pad<<<dim3((2560 * 640 + 255) / 256), blk, 0, stream>>>(linw, wtb, 2524, 2524, 2560, 2560, 0, 0);
  gemm256<<<dim3(640), blk5, 0, stream>>>(atb, DK, wtb, DK, hidb, DK,
                                          DIM, 2560, DK, lin_bias, nullptr, 0, 10, 4);
  k_logprob<<<dim3(NTOK / 4), blk, 0, stream>>>(hidb, fcw, fcb, out);
}